// Round 2
// 120.021 us; speedup vs baseline: 1.1544x; 1.1544x over previous
//
#include <hip/hip_runtime.h>

#define R_DIM 2048
#define O_DIM 32
#define I_DIM 16
#define B_DIM 64
#define BB 16   // batch rows per block

typedef _Float16 half4  __attribute__((ext_vector_type(4)));
typedef float    f32x4  __attribute__((ext_vector_type(4)));

struct SplitH4 { half4 h1, h2; };

// 2-way fp16 split of 4 consecutive fp32: x = h1 + h2 + O(2^-22 * x).
// Proven round-0 primitive sequence (cvt_pkrtz + f32 sub + cvt_pkrtz),
// narrowed to 4 elements for the K=16 MFMA.
__device__ __forceinline__ SplitH4 splitf16x4(const float* __restrict__ p) {
    const float4 f = *(const float4*)p;
    const auto a0 = __builtin_amdgcn_cvt_pkrtz(f.x, f.y);
    const auto a1 = __builtin_amdgcn_cvt_pkrtz(f.z, f.w);
    const auto c0 = __builtin_amdgcn_cvt_pkrtz(f.x - (float)a0[0], f.y - (float)a0[1]);
    const auto c1 = __builtin_amdgcn_cvt_pkrtz(f.z - (float)a1[0], f.w - (float)a1[1]);
    SplitH4 s;
    s.h1[0] = (_Float16)a0[0]; s.h1[1] = (_Float16)a0[1];
    s.h1[2] = (_Float16)a1[0]; s.h1[3] = (_Float16)a1[1];
    s.h2[0] = (_Float16)c0[0]; s.h2[1] = (_Float16)c0[1];
    s.h2[2] = (_Float16)c1[0]; s.h2[3] = (_Float16)c1[1];
    return s;
}

// DPP helpers — all stay on the VALU pipe (no DS traffic).
template<int CTRL>
__device__ __forceinline__ float dpp_mv(float v) {
    int t = __builtin_amdgcn_update_dpp(0, __float_as_int(v), CTRL, 0xf, 0xf, true);
    return __int_as_float(t);
}
__device__ __forceinline__ float row16_sum(float v) {
    v += dpp_mv<0xB1>(v);    // quad_perm xor1
    v += dpp_mv<0x4E>(v);    // quad_perm xor2
    v += dpp_mv<0x124>(v);   // row_ror:4
    v += dpp_mv<0x128>(v);   // row_ror:8
    return v;
}
__device__ __forceinline__ float row16_max(float v) {
    v = fmaxf(v, dpp_mv<0xB1>(v));
    v = fmaxf(v, dpp_mv<0x4E>(v));
    v = fmaxf(v, dpp_mv<0x124>(v));
    v = fmaxf(v, dpp_mv<0x128>(v));
    return v;
}
// row_ror:1 — dst[n] = src[(n-1)&15];  row_ror:2 — dst[n] = src[(n-2)&15]
__device__ __forceinline__ float ror1(float v) { return dpp_mv<0x121>(v); }
__device__ __forceinline__ float ror2(float v) { return dpp_mv<0x122>(v); }

// Block: 512 threads = 8 waves; one (r, 16-batch slice); 32 KB LDS ->
// 4 blocks/CU = 32 waves/CU cap.
// Phase 1 (all 8 waves): u_hat[16b x 512n] via 3-term fp16-split MFMA,
//   16x16x16 (K matches I_DIM=16 -> ALL 64 lanes carry real data; the old
//   x32 version zero-padded half the wave but still paid its split instrs).
// Phase 2 (barrier-free, first 256 lanes): thread=(b,j) owns o={2j,2j+1};
//   lane j holds logit bv[c=j]; systolic ror2 dual-chains for 2x DPP ILP.
__global__ __launch_bounds__(512, 8)
void capsule_routing_kernel(const float* __restrict__ x,
                            const float* __restrict__ W,
                            float* __restrict__ out) {
    __shared__ float u_lds[BB * 512];   // 32 KB

    const int tid = threadIdx.x;
    // XCD-grouping remap: the 4 batch-slice blocks of one r get blockIdx
    // values 8 apart -> same XCD (round-robin %8), co-resident -> W[r]'s
    // 32 KB is fetched from HBM ~once per r instead of ~2x.
    const int bid = blockIdx.x;
    const int r   = ((bid >> 5) << 3) | (bid & 7);
    const int b0  = ((bid >> 3) & 3) * BB;

    // ---------------- Phase 1: fp16-split MFMA u_hat ----------------
    {
        const int lane = tid & 63;
        const int w    = tid >> 6;     // wave 0..7 -> n-tiles 4w..4w+3
        const int q    = lane >> 4;    // k-quad 0..3 (all valid, K=16)
        const int np   = lane & 15;    // m (batch) for A / n-col for B

        const SplitH4 as = splitf16x4(x + ((size_t)(b0 + np) * R_DIM + r) * I_DIM + q * 4);

        const float* Wbase = W + (size_t)r * 8192 + (size_t)(w * 4) * 256 + np * 16 + q * 4;

        const f32x4 zero4 = {0.f, 0.f, 0.f, 0.f};
        #pragma unroll
        for (int t = 0; t < 4; ++t) {
            const int ntile = w * 4 + t;
            const SplitH4 bs = splitf16x4(Wbase + t * 256);

            f32x4 a = __builtin_amdgcn_mfma_f32_16x16x16f16(as.h2, bs.h1, zero4, 0, 0, 0);
            a = __builtin_amdgcn_mfma_f32_16x16x16f16(as.h1, bs.h2, a, 0, 0, 0);
            a = __builtin_amdgcn_mfma_f32_16x16x16f16(as.h1, bs.h1, a, 0, 0, 0);

            // swaddr((q*4+reg), col) == q*2048 + reg*512 + (col ^ (q<<3) ^ (reg<<3))
            // (((4q+reg)^((4q+reg)>>2))&3 == reg^q, XOR distributes over <<3)
            const int col = ntile * 16 + np;
            const int v0  = col ^ (q << 3);
            float* pb = u_lds + q * 2048;
            pb[v0]               = a[0];
            pb[512  + (v0 ^ 8)]  = a[1];
            pb[1024 + (v0 ^ 16)] = a[2];
            pb[1536 + (v0 ^ 24)] = a[3];
        }
    }
    __syncthreads();

    // ---------------- Phase 2: systolic dynamic routing (lanes 0-255) ----------
    if (tid < 256) {
        const int b = tid >> 4;    // 0..15 local batch (one DPP row per b)
        const int j = tid & 15;    // o-pair index / owner of logit c=j

        // swizzle distributes over disjoint bits: (c*32+2j)^sw == c*32 + (2j^sw)
        const int sw = ((b ^ (b >> 2)) & 3) << 3;
        const float* pb = u_lds + b * 512 + ((2 * j) ^ sw);

        // u2p[k] = u_hat[c=(j-k)&15][o=2j,2j+1]
        float2 u2p[16];
        {
            int c = j;
            #pragma unroll
            for (int k = 0; k < 16; ++k) {
                u2p[k] = *(const float2*)&pb[c * 32];
                c = (c - 1) & 15;
            }
        }

        float bvv = 0.0f;          // logit for c=j (distributed)
        float s0 = 0.f, s1 = 0.f, g = 0.f;

        #pragma unroll
        for (int it = 0; it < 3; ++it) {
            if (it == 0) {
                s0 = 0.f; s1 = 0.f;
                #pragma unroll
                for (int k = 0; k < 16; ++k) { s0 += u2p[k].x; s1 += u2p[k].y; }
                s0 *= 0.0625f; s1 *= 0.0625f;
            } else {
                // softmax at lane c: 1 exp/thread
                const float mx = row16_max(bvv);
                const float e  = __expf(bvv - mx);
                const float Z  = row16_sum(e);
                // s_j = sum_c w_c * u[c][o]; TWO independent ror2 weight
                // chains (even/odd k) double the DPP->VALU dependency ILP.
                float wA = e * __builtin_amdgcn_rcpf(Z);   // w at lane c
                float wB = ror1(wA);
                float sA0 = 0.f, sA1 = 0.f, sB0 = 0.f, sB1 = 0.f;
                #pragma unroll
                for (int m = 0; m < 8; ++m) {
                    if (m) { wA = ror2(wA); wB = ror2(wB); }
                    sA0 = fmaf(wA, u2p[2 * m].x,     sA0);
                    sA1 = fmaf(wA, u2p[2 * m].y,     sA1);
                    sB0 = fmaf(wB, u2p[2 * m + 1].x, sB0);
                    sB1 = fmaf(wB, u2p[2 * m + 1].y, sB1);
                }
                s0 = sA0 + sB0;
                s1 = sA1 + sB1;
            }

            // g = ||s|| / (1 + ||s||^2), norm over 32 o's (16 j-lanes x 2)
            const float nn = row16_sum(fmaf(s0, s0, s1 * s1));
            g = sqrtf(nn) * __builtin_amdgcn_rcpf(1.0f + nn);

            if (it < 2) {
                // t[c] via TWO independent rotating accumulators (ror2 each):
                // chain A term at m: rotated 2(7-m)+2 = 16-2m -> lands at j-2m
                // chain B term at m: rotated 2(7-m)+1 = 15-2m -> lands at j-2m-1
                float accA = 0.f, accB = 0.f;
                #pragma unroll
                for (int m = 0; m < 8; ++m) {
                    if (m) { accA = ror2(accA); accB = ror2(accB); }
                    accA = fmaf(u2p[2 * m].x,     s0, accA);
                    accA = fmaf(u2p[2 * m].y,     s1, accA);
                    accB = fmaf(u2p[2 * m + 1].x, s0, accB);
                    accB = fmaf(u2p[2 * m + 1].y, s1, accB);
                }
                const float acc = ror2(accA) + ror1(accB);
                bvv = fmaf(g, acc, bvv);   // b[c] += g * t[c]
            }
        }

        *(float2*)(out + ((size_t)(b0 + b) * R_DIM + r) * O_DIM + 2 * j)
            = make_float2(g * s0, g * s1);
    }
}

extern "C" void kernel_launch(void* const* d_in, const int* in_sizes, int n_in,
                              void* d_out, int out_size, void* d_ws, size_t ws_size,
                              hipStream_t stream) {
    const float* x   = (const float*)d_in[0];   // [64, 2048, 16]
    const float* W   = (const float*)d_in[1];   // [2048, 16, 32, 16]
    float*       out = (float*)d_out;           // [64, 2048, 32]

    dim3 grid(R_DIM * (B_DIM / BB));            // 8192 blocks
    dim3 block(512);
    hipLaunchKernelGGL(capsule_routing_kernel, grid, block, 0, stream, x, W, out);
}